// Round 3
// baseline (98.316 us; speedup 1.0000x reference)
//
#include <hip/hip_runtime.h>
#include <stdint.h>

// Triplet log-ratio loss — two-sided chunk-binned LDS pair-dots (v3).
// R2 post-mortem: v2 (DMA slice-streaming) landed at ~39us ~= the old gather
// kernel. Model: global_load_lds sustains only ~20 B/cyc/CU (cross-checked vs
// m97 GEMM: 4 blk/CU x 2MB / 157us = 21 B/cyc/CU). v2 stages 1 MB PER CU
// (whole table broadcast) -> ~21us floor + latency => 39us. The metric that
// matters is staged-bytes-per-CU. Fix: bin pair-dots by (chunk(a),chunk(v)),
// 16 chunks x 1024 rows -> 256 bins; each block stages only its TWO chunks
// (2x64KB, reg-staged: dodges the slow DMA path) + chunk norms, then every
// row-read is an LDS hit (same verified random-row ds_read_b32 pattern as v2).
// Pipeline: prep(quant+norms) -> scatter(bin records) -> bin_dot -> finalize.

constexpr int DIM  = 128;
constexpr int NSL  = DIM / 8;     // 16 dimension-slices (1 u32 = 8 int4 / row)
constexpr int NRW  = 16384;       // rows (guarded at launch)
constexpr int CHK  = 1024;        // rows per chunk
constexpr int NCH  = NRW / CHK;   // 16 chunks
constexpr int NBIN = NCH * NCH;   // 256 bins
constexpr int CAP  = 16384;       // record capacity per bin (mean 4096, sigma 64)

#if defined(__has_builtin)
#  if __has_builtin(__builtin_amdgcn_sdot4)
#    define HAS_SDOT4 1
#  endif
#  if __has_builtin(__builtin_amdgcn_sdot8)
#    define HAS_SDOT8 1
#  endif
#endif

__device__ inline int dot4i8(uint32_t a, uint32_t b, int c) {
#ifdef HAS_SDOT4
    return __builtin_amdgcn_sdot4((int)a, (int)b, c, false);
#else
    #pragma unroll
    for (int k = 0; k < 32; k += 8)
        c += ((int)(int8_t)(a >> k)) * ((int)(int8_t)(b >> k));
    return c;
#endif
}

// 8-element signed-int4 dot: c += sum_i sext4(a_i)*sext4(b_i)
__device__ inline int dot8n(uint32_t a, uint32_t b, int c) {
#ifdef HAS_SDOT8
    return __builtin_amdgcn_sdot8((int)a, (int)b, c, false);
#else
    // nibble-plane fallback: bytes hold 16*q -> results carry 256x factor
    uint32_t ae = (a << 4) & 0xF0F0F0F0u, ao = a & 0xF0F0F0F0u;
    uint32_t be = (b << 4) & 0xF0F0F0F0u, bo = b & 0xF0F0F0F0u;
    c = dot4i8(ae, be, c);
    return dot4i8(ao, bo, c);
#endif
}

#ifdef HAS_SDOT8
constexpr float SC = 36.0f / 49.0f;            // (6/7)^2, q = round(x*7/6)
#else
constexpr float SC = 36.0f / 49.0f / 256.0f;   // fallback dots (and norms) are 256x
#endif

constexpr float QK = 7.0f / 6.0f;

// ---- prep: fp32 -> int4 slice-major + per-row int norms + zero out/gcnt ----
__global__ __launch_bounds__(256) void prep_q4s_kernel(
    const float4* __restrict__ x4, uint32_t* __restrict__ xqs,
    int* __restrict__ nrm, uint32_t* __restrict__ gcnt,
    float* __restrict__ out, int nrows)
{
    if (blockIdx.x == 0) {
        if (threadIdx.x == 0) *out = 0.0f;
        if (threadIdx.x < NBIN) gcnt[threadIdx.x] = 0u;
    }
    const int gid = blockIdx.x * 256 + threadIdx.x;
    if (gid >= nrows * 4) return;
    const int r = gid >> 2, j = gid & 3;       // row, 32-dim chunk
    const int base = gid * 8;                  // float4 index
    uint32_t w[4];
    #pragma unroll
    for (int d = 0; d < 4; ++d) {
        const float4 f0 = x4[base + 2 * d];
        const float4 f1 = x4[base + 2 * d + 1];
        uint32_t u = 0;
        const float* f = &f0.x;
        #pragma unroll
        for (int jj = 0; jj < 4; ++jj) {
            int q = max(-7, min(7, __float2int_rn(f[jj] * QK)));
            u |= (uint32_t)(q & 15) << (4 * jj);
        }
        const float* g = &f1.x;
        #pragma unroll
        for (int jj = 0; jj < 4; ++jj) {
            int q = max(-7, min(7, __float2int_rn(g[jj] * QK)));
            u |= (uint32_t)(q & 15) << (4 * jj + 16);
        }
        w[d] = u;
    }
    // per-row norm: 4 lanes/row are a quad (block=256 keeps quads aligned)
    int pa = 0;
    #pragma unroll
    for (int d = 0; d < 4; ++d) pa = dot8n(w[d], w[d], pa);
    pa += __shfl_xor(pa, 1, 64);
    pa += __shfl_xor(pa, 2, 64);
    if (j == 0) nrm[r] = pa;
    // slice-major store: word d = dims [32j+8d, 32j+8d+8) -> slice 4j+d
    #pragma unroll
    for (int d = 0; d < 4; ++d)
        xqs[(4 * j + d) * nrows + r] = w[d];
}

// ---- scatter: triplet -> two pair-records, binned by (chunk(a),chunk(v)) ----
// Record: x = alo | (vlo<<10), y = 2*t + flag (flag: 0=P pair, 1=N pair).
__global__ __launch_bounds__(1024) void bin_scatter_kernel(
    const int* __restrict__ trip, uint32_t* __restrict__ gcnt,
    uint2* __restrict__ grec, int T)
{
    __shared__ uint32_t histo[NBIN];
    __shared__ uint32_t base[NBIN];
    const int tid = threadIdx.x;
    if (tid < NBIN) histo[tid] = 0u;
    __syncthreads();

    const int t = blockIdx.x * 1024 + tid;
    const bool v = (t < T);
    int a = 0, p = 0, n = 0, binP = 0, binN = 0;
    uint32_t rkP = 0, rkN = 0;
    if (v) {
        a = trip[3 * t]; p = trip[3 * t + 1]; n = trip[3 * t + 2];
        const int ca = a >> 10;
        binP = (ca << 4) | (p >> 10);
        binN = (ca << 4) | (n >> 10);
        rkP = atomicAdd(&histo[binP], 1u);
        rkN = atomicAdd(&histo[binN], 1u);
    }
    __syncthreads();
    if (tid < NBIN) base[tid] = atomicAdd(&gcnt[tid], histo[tid]);
    __syncthreads();
    if (v) {
        const uint32_t posP = base[binP] + rkP;
        const uint32_t posN = base[binN] + rkN;
        const uint32_t lo = (uint32_t)(a & (CHK - 1));
        if (posP < CAP)
            grec[(size_t)binP * CAP + posP] =
                make_uint2(lo | ((uint32_t)(p & (CHK - 1)) << 10), (uint32_t)(2 * t));
        if (posN < CAP)
            grec[(size_t)binN * CAP + posN] =
                make_uint2(lo | ((uint32_t)(n & (CHK - 1)) << 10), (uint32_t)(2 * t + 1));
    }
}

// ---- bin_dot: stage 2 chunks in LDS, compute D = |qa - qv|^2 per record ----
__global__ __launch_bounds__(1024) void bin_dot_kernel(
    const uint32_t* __restrict__ xqs, const int* __restrict__ nrm,
    const uint32_t* __restrict__ gcnt, const uint2* __restrict__ grec,
    int* __restrict__ gdall)
{
    __shared__ uint32_t bufA[NSL * CHK];   // 64 KB, slice-major within chunk
    __shared__ uint32_t bufB[NSL * CHK];   // 64 KB
    __shared__ int nA[CHK], nB[CHK];       // 8 KB
    const int tid = threadIdx.x;
    const int bin = blockIdx.x;
    const int ci = bin >> 4, cj = bin & 15;

    // stage chunks: 4096 uint4 each, 4 per thread. Local uint4 u maps to
    // global uint4 (u>>8)*4096 + chunk*256 + (u&255) (slice-major table).
    const uint4* xq4 = (const uint4*)xqs;
    uint4* bA4 = (uint4*)bufA;
    uint4* bB4 = (uint4*)bufB;
    #pragma unroll
    for (int c = 0; c < 4; ++c) {
        const int u = c * 1024 + tid;
        const int g = (u >> 8) * 4096 + (u & 255);
        bA4[u] = xq4[g + ci * 256];
        bB4[u] = xq4[g + cj * 256];
    }
    nA[tid] = nrm[ci * CHK + tid];
    nB[tid] = nrm[cj * CHK + tid];
    __syncthreads();

    const int nrec = min((int)gcnt[bin], CAP);
    const uint2* rb = grec + (size_t)bin * CAP;
    for (int k = tid; k < nrec; k += 1024) {
        const uint2 rec = rb[k];
        const int alo = rec.x & (CHK - 1);
        const int vlo = (rec.x >> 10) & (CHK - 1);
        int AP = 0;
        #pragma unroll
        for (int s = 0; s < NSL; ++s)
            AP = dot8n(bufA[s * CHK + alo], bufB[s * CHK + vlo], AP);
        gdall[rec.y] = nA[alo] + nB[vlo] - 2 * AP;   // int |qa-qv|^2 (>=0)
    }
}

// ---- finalize: per triplet combine DP/DN -> log terms, reduce, atomic ----
__global__ __launch_bounds__(1024) void finalize_kernel(
    const int2* __restrict__ gd2, float* __restrict__ out, int T)
{
    const int tid = threadIdx.x;
    float acc = 0.0f;
    for (int t = blockIdx.x * 1024 + tid; t < T; t += gridDim.x * 1024) {
        const int2 d = gd2[t];
        const float dap = SC * (float)d.x;
        const float dan = SC * (float)d.y;
        const float numer = fmaxf(1.0f + dan, 1e-8f);
        const float denom = fmaxf(2.0f + dap + dan, 1e-8f);
        acc += __log2f(denom) - __log2f(numer);
    }
    acc *= 0.69314718055994531f;               // log2 -> ln
    #pragma unroll
    for (int off = 1; off < 64; off <<= 1)
        acc += __shfl_xor(acc, off, 64);
    __shared__ float ws[16];
    if ((tid & 63) == 0) ws[tid >> 6] = acc;
    __syncthreads();
    if (tid == 0) {
        float s = 0.0f;
        #pragma unroll
        for (int w = 0; w < 16; ++w) s += ws[w];
        atomicAdd(out, s);
    }
}

// ---- fallback (fp32 direct) if ws too small / unexpected shape ----
__global__ __launch_bounds__(256) void triplet_f32_kernel(
    const float* __restrict__ x, const int* __restrict__ trip,
    float* __restrict__ out, int T)
{
    const int lane = threadIdx.x & 63;
    const int g = lane >> 5, jl = lane & 31;
    const int wib = threadIdx.x >> 6;
    const int gw = blockIdx.x * 4 + wib;
    const int nW = gridDim.x * 4;
    const float4* __restrict__ x4 = (const float4*)x;

    float acc = 0.0f;
    const int npairs = (T + 1) >> 1;
    for (int i = gw; i < npairs; i += nW) {
        const int t = 2 * i + g;
        if (t >= T) continue;
        const int a = trip[3*t], p = trip[3*t+1], n = trip[3*t+2];
        const float4 va = x4[a * 32 + jl];
        const float4 vp = x4[p * 32 + jl];
        const float4 vn = x4[n * 32 + jl];
        float d0 = va.x - vp.x, d1 = va.y - vp.y, d2 = va.z - vp.z, d3 = va.w - vp.w;
        float dap = d0*d0 + d1*d1 + d2*d2 + d3*d3;
        d0 = va.x - vn.x; d1 = va.y - vn.y; d2 = va.z - vn.z; d3 = va.w - vn.w;
        float dan = d0*d0 + d1*d1 + d2*d2 + d3*d3;
        #pragma unroll
        for (int off = 1; off < 32; off <<= 1) {
            dap += __shfl_xor(dap, off, 64);
            dan += __shfl_xor(dan, off, 64);
        }
        const float numer = fmaxf(1.0f + dan, 1e-8f);
        const float denom = fmaxf(2.0f + dap + dan, 1e-8f);
        acc += (jl == 0) ? (__logf(denom) - __logf(numer)) : 0.0f;
    }
    #pragma unroll
    for (int off = 1; off < 64; off <<= 1)
        acc += __shfl_xor(acc, off, 64);
    __shared__ float wsum[4];
    if (lane == 0) wsum[wib] = acc;
    __syncthreads();
    if (threadIdx.x == 0)
        atomicAdd(out, wsum[0] + wsum[1] + wsum[2] + wsum[3]);
}

extern "C" void kernel_launch(void* const* d_in, const int* in_sizes, int n_in,
                              void* d_out, int out_size, void* d_ws, size_t ws_size,
                              hipStream_t stream) {
    const float* x  = (const float*)d_in[0];
    const int* trip = (const int*)d_in[1];
    float* out      = (float*)d_out;
    const int T     = in_sizes[1] / 3;
    const int nrows = in_sizes[0] / DIM;

    // workspace layout
    const size_t off_xqs  = 0;              // 1 MB   slice-major int4 table
    const size_t off_nrm  = 0x100000;       // 64 KB  per-row int norms
    const size_t off_cnt  = 0x110000;       // 1 KB   bin counters
    const size_t off_rec  = 0x200000;       // 32 MB  bin records (256 x 16384 x 8B)
    const size_t off_dall = 0x2200000;      // 2T*4B  pair-dists (4 MB)
    const size_t need     = off_dall + (size_t)2 * 524288 * 4;

    if (nrows == NRW && T <= 524288 && ws_size >= need) {
        uint8_t* ws = (uint8_t*)d_ws;
        uint32_t* xqs  = (uint32_t*)(ws + off_xqs);
        int*      nrm  = (int*)     (ws + off_nrm);
        uint32_t* gcnt = (uint32_t*)(ws + off_cnt);
        uint2*    grec = (uint2*)   (ws + off_rec);
        int*      gdal = (int*)     (ws + off_dall);

        const int pblocks = (nrows * 4 + 255) / 256;
        prep_q4s_kernel<<<pblocks, 256, 0, stream>>>(
            (const float4*)x, xqs, nrm, gcnt, out, nrows);
        const int sblocks = (T + 1023) / 1024;
        bin_scatter_kernel<<<sblocks, 1024, 0, stream>>>(trip, gcnt, grec, T);
        bin_dot_kernel<<<NBIN, 1024, 0, stream>>>(xqs, nrm, gcnt, grec, gdal);
        finalize_kernel<<<256, 1024, 0, stream>>>((const int2*)gdal, out, T);
    } else {
        (void)hipMemsetAsync(out, 0, sizeof(float), stream);
        triplet_f32_kernel<<<2048, 256, 0, stream>>>(x, trip, out, T);
    }
}

// Round 4
// 80.505 us; speedup vs baseline: 1.2212x; 1.2212x over previous
//
#include <hip/hip_runtime.h>
#include <stdint.h>

// Triplet log-ratio loss — slice-stream v4 (reg-staged, spill-proof).
// R3 post-mortem: binning pipeline (scatter+bin_dot+finalize) cost ~52us —
// scattered record/dist stores across non-coherent XCD L2s + extra launches
// ate the staging win. Reverted.
// Model from v0/v2/v1: random-L2-gather ~10 B/cyc/CU (v0, 36us);
// global_load_lds drains ~16 B/cyc/CU (v2, 39us: 1 MB/CU staged -> ~27us);
// ds_write_b128 staging ceiling is 128 B/cyc/CU — v1 proved the structure but
// spilled (32-reg stage array + 512thr). v4 = v2's verified slice-stream with
// reg staging sized to NOT spill:
//   1024 thr/block (1 block/CU, 16 waves), 4 named uint4 stage regs/thread
//   (64 KB/slice), 2 triplets/thread (6 idx + 10 acc regs), launch_bounds(1024)
//   => compiler must stay <=128 VGPR. One barrier per pass (write targets the
//   buffer whose reads were fenced by the PREVIOUS barrier). Compute before
//   write = issue-early/write-late (T14): global latency hides under dots.

constexpr int DIM = 128;
constexpr int NSL = DIM / 8;   // 16 dimension-slices (1 u32 = 8 int4 per row)
constexpr int NR  = 16384;     // rows (guarded at launch)

#if defined(__has_builtin)
#  if __has_builtin(__builtin_amdgcn_sdot4)
#    define HAS_SDOT4 1
#  endif
#  if __has_builtin(__builtin_amdgcn_sdot8)
#    define HAS_SDOT8 1
#  endif
#endif

__device__ inline int dot4i8(uint32_t a, uint32_t b, int c) {
#ifdef HAS_SDOT4
    return __builtin_amdgcn_sdot4((int)a, (int)b, c, false);
#else
    #pragma unroll
    for (int k = 0; k < 32; k += 8)
        c += ((int)(int8_t)(a >> k)) * ((int)(int8_t)(b >> k));
    return c;
#endif
}

// 8-element signed-int4 dot: c += sum_i sext4(a_i)*sext4(b_i)
__device__ inline int dot8n(uint32_t a, uint32_t b, int c) {
#ifdef HAS_SDOT8
    return __builtin_amdgcn_sdot8((int)a, (int)b, c, false);
#else
    // nibble-plane fallback: bytes hold 16*q -> results carry 256x factor
    uint32_t ae = (a << 4) & 0xF0F0F0F0u, ao = a & 0xF0F0F0F0u;
    uint32_t be = (b << 4) & 0xF0F0F0F0u, bo = b & 0xF0F0F0F0u;
    c = dot4i8(ae, be, c);
    return dot4i8(ao, bo, c);
#endif
}

#ifdef HAS_SDOT8
constexpr float SC = 36.0f / 49.0f;            // (6/7)^2, q = round(x*7/6)
#else
constexpr float SC = 36.0f / 49.0f / 256.0f;   // fallback dots are 256x
#endif

constexpr float QK = 7.0f / 6.0f;

// ---- prep: fp32 -> int4, slice-major layout (+ zero out). 4 thr/row ----
__global__ __launch_bounds__(256) void prep_q4s_kernel(
    const float4* __restrict__ x4, uint32_t* __restrict__ xqs,
    float* __restrict__ out, int nrows)
{
    if (blockIdx.x == 0 && threadIdx.x == 0) *out = 0.0f;
    const int gid = blockIdx.x * 256 + threadIdx.x;
    if (gid >= nrows * 4) return;
    const int r = gid >> 2, j = gid & 3;       // row, 32-dim chunk
    const int base = gid * 8;                  // float4 index
    uint32_t w[4];
    #pragma unroll
    for (int d = 0; d < 4; ++d) {
        const float4 f0 = x4[base + 2 * d];
        const float4 f1 = x4[base + 2 * d + 1];
        uint32_t u = 0;
        const float* f = &f0.x;
        #pragma unroll
        for (int jj = 0; jj < 4; ++jj) {
            int q = max(-7, min(7, __float2int_rn(f[jj] * QK)));
            u |= (uint32_t)(q & 15) << (4 * jj);
        }
        const float* g = &f1.x;
        #pragma unroll
        for (int jj = 0; jj < 4; ++jj) {
            int q = max(-7, min(7, __float2int_rn(g[jj] * QK)));
            u |= (uint32_t)(q & 15) << (4 * jj + 16);
        }
        w[d] = u;
    }
    // slice-major store: word d = dims [32j+8d, 32j+8d+8) -> slice 4j+d
    #pragma unroll
    for (int d = 0; d < 4; ++d)
        xqs[(4 * j + d) * nrows + r] = w[d];
}

// ---- main: reg-staged LDS slice passes, double-buffered, 1 barrier/pass ----
__global__ __launch_bounds__(1024) void triplet_lds3_kernel(
    const uint32_t* __restrict__ xqs, const int* __restrict__ trip,
    float* __restrict__ out, int T)
{
    __shared__ uint32_t buf[2][NR];            // 2 x 64 KB double buffer
    __shared__ float wsum[16];
    const int tid = threadIdx.x;
    const int gid = blockIdx.x * 1024 + tid;
    const int t0 = 2 * gid;
    const bool v0 = (t0 < T), v1 = (t0 + 1 < T);

    // ---- 6 indices/thread, loaded once, live in VGPRs for all 16 passes ----
    int a0 = 0, p0 = 0, n0 = 0, a1 = 0, p1 = 0, n1 = 0;
    if (v1) {
        const int2* tp2 = (const int2*)trip + (size_t)3 * gid;  // 8-B aligned
        const int2 w0 = tp2[0], w1 = tp2[1], w2 = tp2[2];
        a0 = w0.x; p0 = w0.y; n0 = w1.x;
        a1 = w1.y; p1 = w2.x; n1 = w2.y;
    } else if (v0) {
        a0 = trip[3 * t0]; p0 = trip[3 * t0 + 1]; n0 = trip[3 * t0 + 2];
    }

    int AA0 = 0, PP0 = 0, NN0 = 0, AP0 = 0, AN0 = 0;
    int AA1 = 0, PP1 = 0, NN1 = 0, AP1 = 0, AN1 = 0;

    // ---- prologue: stage slice 0 (4 named uint4 regs/thread = 64 KB) ----
    const uint4* src0 = (const uint4*)xqs;     // slice s = src0 + s*4096
    uint4 s0, s1, s2, s3;
    s0 = src0[tid];        s1 = src0[1024 + tid];
    s2 = src0[2048 + tid]; s3 = src0[3072 + tid];
    {
        uint4* d = (uint4*)buf[0];
        d[tid] = s0;        d[1024 + tid] = s1;
        d[2048 + tid] = s2; d[3072 + tid] = s3;
    }
    __syncthreads();

    int cur = 0;
    for (int s = 0; s < NSL; ++s) {
        if (s + 1 < NSL) {                     // issue next slice's loads EARLY
            const uint4* src = src0 + (size_t)(s + 1) * 4096;
            s0 = src[tid];        s1 = src[1024 + tid];
            s2 = src[2048 + tid]; s3 = src[3072 + tid];
        }
        const uint32_t* bf = buf[cur];
        const uint32_t wa0 = bf[a0], wp0 = bf[p0], wn0 = bf[n0];
        const uint32_t wa1 = bf[a1], wp1 = bf[p1], wn1 = bf[n1];
        AA0 = dot8n(wa0, wa0, AA0); PP0 = dot8n(wp0, wp0, PP0);
        NN0 = dot8n(wn0, wn0, NN0); AP0 = dot8n(wa0, wp0, AP0);
        AN0 = dot8n(wa0, wn0, AN0);
        AA1 = dot8n(wa1, wa1, AA1); PP1 = dot8n(wp1, wp1, PP1);
        NN1 = dot8n(wn1, wn1, NN1); AP1 = dot8n(wa1, wp1, AP1);
        AN1 = dot8n(wa1, wn1, AN1);
        if (s + 1 < NSL) {
            // write-late into the OTHER buffer: its last reads (pass s-1)
            // were fenced by the previous barrier -> one barrier per pass.
            uint4* d = (uint4*)buf[cur ^ 1];
            d[tid] = s0;        d[1024 + tid] = s1;
            d[2048 + tid] = s2; d[3072 + tid] = s3;
            __syncthreads();
            cur ^= 1;
        }
    }

    // ---- finish: log terms, block reduce, one atomic ----
    float acc = 0.0f;
    {
        const float dap = SC * (float)(AA0 + PP0 - 2 * AP0);
        const float dan = SC * (float)(AA0 + NN0 - 2 * AN0);
        const float numer = fmaxf(1.0f + dan, 1e-8f);
        const float denom = fmaxf(2.0f + dap + dan, 1e-8f);
        acc += v0 ? (__log2f(denom) - __log2f(numer)) : 0.0f;
    }
    {
        const float dap = SC * (float)(AA1 + PP1 - 2 * AP1);
        const float dan = SC * (float)(AA1 + NN1 - 2 * AN1);
        const float numer = fmaxf(1.0f + dan, 1e-8f);
        const float denom = fmaxf(2.0f + dap + dan, 1e-8f);
        acc += v1 ? (__log2f(denom) - __log2f(numer)) : 0.0f;
    }
    acc *= 0.69314718055994531f;               // log2 -> ln
    #pragma unroll
    for (int off = 1; off < 64; off <<= 1)
        acc += __shfl_xor(acc, off, 64);

    if ((tid & 63) == 0) wsum[tid >> 6] = acc;
    __syncthreads();
    if (tid == 0) {
        float s8 = 0.0f;
        #pragma unroll
        for (int w = 0; w < 16; ++w) s8 += wsum[w];
        atomicAdd(out, s8);
    }
}

// ---- fallback (fp32 direct) if ws too small / unexpected shape ----
__global__ __launch_bounds__(256) void triplet_f32_kernel(
    const float* __restrict__ x, const int* __restrict__ trip,
    float* __restrict__ out, int T)
{
    const int lane = threadIdx.x & 63;
    const int g = lane >> 5, jl = lane & 31;
    const int wib = threadIdx.x >> 6;
    const int gw = blockIdx.x * 4 + wib;
    const int nW = gridDim.x * 4;
    const float4* __restrict__ x4 = (const float4*)x;

    float acc = 0.0f;
    const int npairs = (T + 1) >> 1;
    for (int i = gw; i < npairs; i += nW) {
        const int t = 2 * i + g;
        if (t >= T) continue;
        const int a = trip[3*t], p = trip[3*t+1], n = trip[3*t+2];
        const float4 va = x4[a * 32 + jl];
        const float4 vp = x4[p * 32 + jl];
        const float4 vn = x4[n * 32 + jl];
        float d0 = va.x - vp.x, d1 = va.y - vp.y, d2 = va.z - vp.z, d3 = va.w - vp.w;
        float dap = d0*d0 + d1*d1 + d2*d2 + d3*d3;
        d0 = va.x - vn.x; d1 = va.y - vn.y; d2 = va.z - vn.z; d3 = va.w - vn.w;
        float dan = d0*d0 + d1*d1 + d2*d2 + d3*d3;
        #pragma unroll
        for (int off = 1; off < 32; off <<= 1) {
            dap += __shfl_xor(dap, off, 64);
            dan += __shfl_xor(dan, off, 64);
        }
        const float numer = fmaxf(1.0f + dan, 1e-8f);
        const float denom = fmaxf(2.0f + dap + dan, 1e-8f);
        acc += (jl == 0) ? (__logf(denom) - __logf(numer)) : 0.0f;
    }
    #pragma unroll
    for (int off = 1; off < 64; off <<= 1)
        acc += __shfl_xor(acc, off, 64);
    __shared__ float wsum[4];
    if (lane == 0) wsum[wib] = acc;
    __syncthreads();
    if (threadIdx.x == 0)
        atomicAdd(out, wsum[0] + wsum[1] + wsum[2] + wsum[3]);
}

extern "C" void kernel_launch(void* const* d_in, const int* in_sizes, int n_in,
                              void* d_out, int out_size, void* d_ws, size_t ws_size,
                              hipStream_t stream) {
    const float* x  = (const float*)d_in[0];
    const int* trip = (const int*)d_in[1];
    float* out      = (float*)d_out;
    const int T     = in_sizes[1] / 3;
    const int nrows = in_sizes[0] / DIM;

    const size_t xqs_bytes = (size_t)nrows * (DIM / 2);   // 1 MB slice-major table
    if (nrows == NR && ws_size >= xqs_bytes) {
        uint32_t* xqs = (uint32_t*)d_ws;
        const int cblocks = (nrows * 4 + 255) / 256;
        prep_q4s_kernel<<<cblocks, 256, 0, stream>>>((const float4*)x, xqs, out, nrows);
        const int blocks = (T + 2047) / 2048;             // 1024 thr x 2 triplets
        triplet_lds3_kernel<<<blocks, 1024, 0, stream>>>(xqs, trip, out, T);
    } else {
        (void)hipMemsetAsync(out, 0, sizeof(float), stream);
        triplet_f32_kernel<<<2048, 256, 0, stream>>>(x, trip, out, T);
    }
}

// Round 5
// 80.033 us; speedup vs baseline: 1.2284x; 1.0059x over previous
//
#include <hip/hip_runtime.h>
#include <stdint.h>

// Triplet log-ratio loss — slice-stream v5 (stagger + norm table).
// Accounting across R0-R4 (R1's directly-measured main=80us anchors a ~12us
// per-iteration launch/replay overhead): fill 42 + overhead 12 = ~54us fixed
// harness floor; our kernels ~26us (v4 main ~24). Remaining gap vs the ~11us
// model: (1) synchronized post-barrier staging bursts — all 32 CUs/XCD pull
// the SAME 64KB slice from L2 at once (~1.2Kcyc exposed in vmcnt wait);
// (2) 12 of 20 dots/thread/pass compute per-ROW self-norms.
// v5: (a) per-block slice-order stagger (phase=(b>>3)&15 spreads each XCD's
// CUs over all 16 slices -> staging overlaps compute; integer sum over a
// permutation of slices is bit-identical); (b) prep emits per-row int norms
// (verified v3 code); per-pass dots drop 10->4; norms staged into the freed
// LDS buffer after the last pass (coalesced, no random-global tail).

constexpr int DIM = 128;
constexpr int NSL = DIM / 8;   // 16 dimension-slices (1 u32 = 8 int4 per row)
constexpr int NR  = 16384;     // rows (guarded at launch)

#if defined(__has_builtin)
#  if __has_builtin(__builtin_amdgcn_sdot4)
#    define HAS_SDOT4 1
#  endif
#  if __has_builtin(__builtin_amdgcn_sdot8)
#    define HAS_SDOT8 1
#  endif
#endif

__device__ inline int dot4i8(uint32_t a, uint32_t b, int c) {
#ifdef HAS_SDOT4
    return __builtin_amdgcn_sdot4((int)a, (int)b, c, false);
#else
    #pragma unroll
    for (int k = 0; k < 32; k += 8)
        c += ((int)(int8_t)(a >> k)) * ((int)(int8_t)(b >> k));
    return c;
#endif
}

// 8-element signed-int4 dot: c += sum_i sext4(a_i)*sext4(b_i)
__device__ inline int dot8n(uint32_t a, uint32_t b, int c) {
#ifdef HAS_SDOT8
    return __builtin_amdgcn_sdot8((int)a, (int)b, c, false);
#else
    // nibble-plane fallback: bytes hold 16*q -> results carry 256x factor
    uint32_t ae = (a << 4) & 0xF0F0F0F0u, ao = a & 0xF0F0F0F0u;
    uint32_t be = (b << 4) & 0xF0F0F0F0u, bo = b & 0xF0F0F0F0u;
    c = dot4i8(ae, be, c);
    return dot4i8(ao, bo, c);
#endif
}

#ifdef HAS_SDOT8
constexpr float SC = 36.0f / 49.0f;            // (6/7)^2, q = round(x*7/6)
#else
constexpr float SC = 36.0f / 49.0f / 256.0f;   // fallback dots AND norms are 256x
#endif

constexpr float QK = 7.0f / 6.0f;

// ---- prep: fp32 -> int4 slice-major + per-row int norms (+ zero out) ----
__global__ __launch_bounds__(256) void prep_q4s_kernel(
    const float4* __restrict__ x4, uint32_t* __restrict__ xqs,
    int* __restrict__ nrm, float* __restrict__ out, int nrows)
{
    if (blockIdx.x == 0 && threadIdx.x == 0) *out = 0.0f;
    const int gid = blockIdx.x * 256 + threadIdx.x;
    if (gid >= nrows * 4) return;
    const int r = gid >> 2, j = gid & 3;       // row, 32-dim chunk
    const int base = gid * 8;                  // float4 index
    uint32_t w[4];
    #pragma unroll
    for (int d = 0; d < 4; ++d) {
        const float4 f0 = x4[base + 2 * d];
        const float4 f1 = x4[base + 2 * d + 1];
        uint32_t u = 0;
        const float* f = &f0.x;
        #pragma unroll
        for (int jj = 0; jj < 4; ++jj) {
            int q = max(-7, min(7, __float2int_rn(f[jj] * QK)));
            u |= (uint32_t)(q & 15) << (4 * jj);
        }
        const float* g = &f1.x;
        #pragma unroll
        for (int jj = 0; jj < 4; ++jj) {
            int q = max(-7, min(7, __float2int_rn(g[jj] * QK)));
            u |= (uint32_t)(q & 15) << (4 * jj + 16);
        }
        w[d] = u;
    }
    // per-row norm: 4 lanes/row form an aligned quad (blockDim=256)
    int pa = 0;
    #pragma unroll
    for (int d = 0; d < 4; ++d) pa = dot8n(w[d], w[d], pa);
    pa += __shfl_xor(pa, 1, 64);
    pa += __shfl_xor(pa, 2, 64);
    if (j == 0) nrm[r] = pa;
    // slice-major store: word d = dims [32j+8d, 32j+8d+8) -> slice 4j+d
    #pragma unroll
    for (int d = 0; d < 4; ++d)
        xqs[(4 * j + d) * nrows + r] = w[d];
}

// ---- main: staggered reg-staged slice passes, norms from table ----
__global__ __launch_bounds__(1024) void triplet_lds5_kernel(
    const uint32_t* __restrict__ xqs, const int* __restrict__ nrm,
    const int* __restrict__ trip, float* __restrict__ out, int T)
{
    __shared__ uint32_t buf[2][NR];            // 2 x 64 KB double buffer
    __shared__ float wsum[16];
    const int tid = threadIdx.x;
    const int gid = blockIdx.x * 1024 + tid;
    const int t0 = 2 * gid;
    const bool v0 = (t0 < T), v1 = (t0 + 1 < T);

    // ---- 6 indices/thread, loaded once, live in VGPRs for all 16 passes ----
    int a0 = 0, p0 = 0, n0 = 0, a1 = 0, p1 = 0, n1 = 0;
    if (v1) {
        const int2* tp2 = (const int2*)trip + (size_t)3 * gid;  // 8-B aligned
        const int2 w0 = tp2[0], w1 = tp2[1], w2 = tp2[2];
        a0 = w0.x; p0 = w0.y; n0 = w1.x;
        a1 = w1.y; p1 = w2.x; n1 = w2.y;
    } else if (v0) {
        a0 = trip[3 * t0]; p0 = trip[3 * t0 + 1]; n0 = trip[3 * t0 + 2];
    }

    int AP0 = 0, AN0 = 0, AP1 = 0, AN1 = 0;

    // stagger: blocks 0-7 (one per XCD) share phase 0, 8-15 phase 1, ... so
    // each XCD's 32 CUs spread across all 16 slices -> desynced L2 bursts.
    const int phase = (blockIdx.x >> 3) & 15;
    const uint4* src0 = (const uint4*)xqs;     // slice ss at src0 + ss*4096

    // ---- prologue: stage slice 'phase' (4 named uint4 regs = 64 KB) ----
    uint4 s0, s1, s2, s3;
    {
        const uint4* src = src0 + (size_t)phase * 4096;
        s0 = src[tid];        s1 = src[1024 + tid];
        s2 = src[2048 + tid]; s3 = src[3072 + tid];
        uint4* d = (uint4*)buf[0];
        d[tid] = s0;        d[1024 + tid] = s1;
        d[2048 + tid] = s2; d[3072 + tid] = s3;
    }
    __syncthreads();

    int cur = 0;
    for (int s = 0; s < NSL; ++s) {
        if (s + 1 < NSL) {                     // issue next slice's loads EARLY
            const uint4* src = src0 + (size_t)(((phase + s + 1) & 15)) * 4096;
            s0 = src[tid];        s1 = src[1024 + tid];
            s2 = src[2048 + tid]; s3 = src[3072 + tid];
        }
        const uint32_t* bf = buf[cur];
        const uint32_t wa0 = bf[a0], wp0 = bf[p0], wn0 = bf[n0];
        const uint32_t wa1 = bf[a1], wp1 = bf[p1], wn1 = bf[n1];
        AP0 = dot8n(wa0, wp0, AP0); AN0 = dot8n(wa0, wn0, AN0);
        AP1 = dot8n(wa1, wp1, AP1); AN1 = dot8n(wa1, wn1, AN1);
        if (s + 1 < NSL) {
            // write-late into the OTHER buffer (its reads fenced last barrier)
            uint4* d = (uint4*)buf[cur ^ 1];
            d[tid] = s0;        d[1024 + tid] = s1;
            d[2048 + tid] = s2; d[3072 + tid] = s3;
            __syncthreads();
            cur ^= 1;
        }
    }

    // ---- stage norm table (64 KB) into buf[0]; last pass read buf[1], and
    // buf[0]'s last reads were fenced by the pass-14 barrier -> safe.
    {
        const uint4* srcn = (const uint4*)nrm;
        const uint4 n0v = srcn[tid],        n1v = srcn[1024 + tid];
        const uint4 n2v = srcn[2048 + tid], n3v = srcn[3072 + tid];
        uint4* d = (uint4*)buf[0];
        d[tid] = n0v;        d[1024 + tid] = n1v;
        d[2048 + tid] = n2v; d[3072 + tid] = n3v;
    }
    __syncthreads();
    const int* nb = (const int*)buf[0];

    // ---- finish: log terms, block reduce, one atomic ----
    float acc = 0.0f;
    {
        const float dap = SC * (float)(nb[a0] + nb[p0] - 2 * AP0);
        const float dan = SC * (float)(nb[a0] + nb[n0] - 2 * AN0);
        const float numer = fmaxf(1.0f + dan, 1e-8f);
        const float denom = fmaxf(2.0f + dap + dan, 1e-8f);
        acc += v0 ? (__log2f(denom) - __log2f(numer)) : 0.0f;
    }
    {
        const float dap = SC * (float)(nb[a1] + nb[p1] - 2 * AP1);
        const float dan = SC * (float)(nb[a1] + nb[n1] - 2 * AN1);
        const float numer = fmaxf(1.0f + dan, 1e-8f);
        const float denom = fmaxf(2.0f + dap + dan, 1e-8f);
        acc += v1 ? (__log2f(denom) - __log2f(numer)) : 0.0f;
    }
    acc *= 0.69314718055994531f;               // log2 -> ln
    #pragma unroll
    for (int off = 1; off < 64; off <<= 1)
        acc += __shfl_xor(acc, off, 64);

    if ((tid & 63) == 0) wsum[tid >> 6] = acc;
    __syncthreads();
    if (tid == 0) {
        float s8 = 0.0f;
        #pragma unroll
        for (int w = 0; w < 16; ++w) s8 += wsum[w];
        atomicAdd(out, s8);
    }
}

// ---- fallback (fp32 direct) if ws too small / unexpected shape ----
__global__ __launch_bounds__(256) void triplet_f32_kernel(
    const float* __restrict__ x, const int* __restrict__ trip,
    float* __restrict__ out, int T)
{
    const int lane = threadIdx.x & 63;
    const int g = lane >> 5, jl = lane & 31;
    const int wib = threadIdx.x >> 6;
    const int gw = blockIdx.x * 4 + wib;
    const int nW = gridDim.x * 4;
    const float4* __restrict__ x4 = (const float4*)x;

    float acc = 0.0f;
    const int npairs = (T + 1) >> 1;
    for (int i = gw; i < npairs; i += nW) {
        const int t = 2 * i + g;
        if (t >= T) continue;
        const int a = trip[3*t], p = trip[3*t+1], n = trip[3*t+2];
        const float4 va = x4[a * 32 + jl];
        const float4 vp = x4[p * 32 + jl];
        const float4 vn = x4[n * 32 + jl];
        float d0 = va.x - vp.x, d1 = va.y - vp.y, d2 = va.z - vp.z, d3 = va.w - vp.w;
        float dap = d0*d0 + d1*d1 + d2*d2 + d3*d3;
        d0 = va.x - vn.x; d1 = va.y - vn.y; d2 = va.z - vn.z; d3 = va.w - vn.w;
        float dan = d0*d0 + d1*d1 + d2*d2 + d3*d3;
        #pragma unroll
        for (int off = 1; off < 32; off <<= 1) {
            dap += __shfl_xor(dap, off, 64);
            dan += __shfl_xor(dan, off, 64);
        }
        const float numer = fmaxf(1.0f + dan, 1e-8f);
        const float denom = fmaxf(2.0f + dap + dan, 1e-8f);
        acc += (jl == 0) ? (__logf(denom) - __logf(numer)) : 0.0f;
    }
    #pragma unroll
    for (int off = 1; off < 64; off <<= 1)
        acc += __shfl_xor(acc, off, 64);
    __shared__ float wsum[4];
    if (lane == 0) wsum[wib] = acc;
    __syncthreads();
    if (threadIdx.x == 0)
        atomicAdd(out, wsum[0] + wsum[1] + wsum[2] + wsum[3]);
}

extern "C" void kernel_launch(void* const* d_in, const int* in_sizes, int n_in,
                              void* d_out, int out_size, void* d_ws, size_t ws_size,
                              hipStream_t stream) {
    const float* x  = (const float*)d_in[0];
    const int* trip = (const int*)d_in[1];
    float* out      = (float*)d_out;
    const int T     = in_sizes[1] / 3;
    const int nrows = in_sizes[0] / DIM;

    // workspace layout: xqs 1 MB @0, nrm 64 KB @1 MB
    const size_t off_nrm = 0x100000;
    const size_t need    = off_nrm + (size_t)NR * 4;
    if (nrows == NR && ws_size >= need) {
        uint32_t* xqs = (uint32_t*)d_ws;
        int*      nrm = (int*)((uint8_t*)d_ws + off_nrm);
        const int cblocks = (nrows * 4 + 255) / 256;
        prep_q4s_kernel<<<cblocks, 256, 0, stream>>>(
            (const float4*)x, xqs, nrm, out, nrows);
        const int blocks = (T + 2047) / 2048;             // 1024 thr x 2 triplets
        triplet_lds5_kernel<<<blocks, 1024, 0, stream>>>(xqs, nrm, trip, out, T);
    } else {
        (void)hipMemsetAsync(out, 0, sizeof(float), stream);
        triplet_f32_kernel<<<2048, 256, 0, stream>>>(x, trip, out, T);
    }
}